// Round 3
// baseline (1226.319 us; speedup 1.0000x reference)
//
#include <hip/hip_runtime.h>

// Problem constants: B=16, T=4096, D=256, K=1024
#define N_TOK 65536
#define DIM   256
#define KCODE 1024

#define NTHREADS 256
#define TM 128          // tokens per block
#define TN 128          // codes per block
#define NCHUNK 8        // code chunks (1024/128)
#define NSTAGE 24       // 3 segments x 8 k-chunks of 32

// fp32 gap below which the top-2 go to fp64 refinement (bf16x3 dot err ~1e-2 bound)
#define REFINE_EPS 0.125f
// fp64 gap below which the reference's fp32 pipeline likely collapsed the two
// distances onto the same fp32 grid point -> first-occurrence -> LOWER index.
#define TIE_THETA 1.0e-4

// ws layout (floats):
//   [0]                    loss accum
//   [16 .. 16+1024)        c_sq (numpy-pairwise-exact)
//   [2048 .. +65536)       idx (int) final argmin
//   [67584 .. +8*4*65536)  pairs (float4, chunk-major: pairs[c*N_TOK + t])
//   [then]                 cb packed tile-major bf16 hi/lo (1 MB)
#define WS_CSQ_OFF   16
#define WS_IDX_OFF   2048
#define WS_PAIRS_OFF (WS_IDX_OFF + N_TOK)
#define WS_CBPK_OFF  (WS_PAIRS_OFF + N_TOK * NCHUNK * 4)

typedef float f32x4  __attribute__((ext_vector_type(4)));
typedef short bf16x8 __attribute__((ext_vector_type(8)));
typedef short s16x8  __attribute__((ext_vector_type(8)));

__global__ void zero_loss_kernel(float* ws) {
    if (threadIdx.x == 0) ws[0] = 0.0f;
}

// numpy-pairwise-exact row sum-of-squares for [rows, 256] fp32 (codebook).
__global__ void rowsq_np_kernel(const float* __restrict__ m,
                                float* __restrict__ out, int rows) {
#pragma clang fp contract(off)
    int row = blockIdx.x * 16 + (threadIdx.x >> 4);
    int l   = threadIdx.x & 15;
    if (row >= rows) return;
    int h = l >> 3;
    int j = l & 7;
    const float* p = m + (size_t)row * DIM + h * 128 + j;
    float v = p[0];
    float r = v * v;
#pragma unroll
    for (int i = 1; i < 16; ++i) {
        float w  = p[i * 8];
        float w2 = w * w;
        r = r + w2;
    }
    float t = r + __shfl_xor(r, 1);
    t = t + __shfl_xor(t, 2);
    t = t + __shfl_xor(t, 4);
    t = t + __shfl_xor(t, 8);
    if (l == 0) out[row] = t;
}

// Insert (d, idx) into a sorted top-2 with lower-index tie-break.
__device__ __forceinline__ void ins2(float d, int idx,
                                     float& d1, int& i1, float& d2, int& i2) {
    if (d < d1 || (d == d1 && idx < i1)) {
        d2 = d1; i2 = i1; d1 = d; i1 = idx;
    } else if ((d < d2 || (d == d2 && idx < i2)) && idx != i1) {
        d2 = d; i2 = idx;
    }
}

// RNE fp32 -> bf16 split: v = hi + lo with lo capturing the residual.
__device__ __forceinline__ void f2bf_split(float v, short& hi, short& lo) {
    unsigned u = __float_as_uint(v);
    unsigned r = (u + 0x7fffu + ((u >> 16) & 1u)) >> 16;
    hi = (short)r;
    float hf = __uint_as_float(r << 16);
    float lf = v - hf;
    unsigned u2 = __float_as_uint(lf);
    unsigned r2 = (u2 + 0x7fffu + ((u2 >> 16) & 1u)) >> 16;
    lo = (short)r2;
}

// R3: tile-major pack, NO swizzle (no LDS in the consumer anymore).
// Output: chunk c = (g*16 + part*8 + kc), each chunk 128 rows x 32 shorts
// (8 KB contiguous). Row r slot s (8 shorts) = k-octet s of k-range
// [kc*32, kc*32+32). part: 0 = bf16 hi, 8 = bf16 lo.
// Thread (g, kc, r, s): reads 8 fp32, writes 16B hi + 16B lo, all coalesced.
__global__ void pack_tiles_kernel(const float* __restrict__ src,
                                  unsigned short* __restrict__ dst,
                                  int total) {       // total = rows * 32
    int tid = blockIdx.x * blockDim.x + threadIdx.x;
    if (tid >= total) return;
    int s   = tid & 3;
    int r   = (tid >> 2) & 127;
    int kc  = (tid >> 9) & 7;
    int g   = tid >> 12;

    const float4* xr = reinterpret_cast<const float4*>(
        src + ((size_t)(g * 128 + r)) * DIM + kc * 32 + s * 8);
    float4 v0 = xr[0];
    float4 v1 = xr[1];

    float f[8] = {v0.x, v0.y, v0.z, v0.w, v1.x, v1.y, v1.z, v1.w};
    s16x8 hv, lv;
#pragma unroll
    for (int i = 0; i < 8; ++i) {
        short h, l;
        f2bf_split(f[i], h, l);
        hv[i] = h; lv[i] = l;
    }
    size_t base_hi = (((size_t)(g * 16 + kc) * 128 + r) << 5) + s * 8;
    size_t base_lo = (((size_t)(g * 16 + 8 + kc) * 128 + r) << 5) + s * 8;
    *reinterpret_cast<s16x8*>(dst + base_hi) = hv;
    *reinterpret_cast<s16x8*>(dst + base_lo) = lv;
}

// MFMA distance + top-2. dist' = c_sq - 2*(x.c); ||x||^2 dropped (cancels).
// dot = hi*hi + hi*lo + lo*hi as one K=768 concat-GEMM over 3 segments.
//
// R3 restructure: NO LDS, NO barriers in the K-loop. R0-R2 showed the
// per-stage vmcnt(0)+barrier drain cost ~14K cycles/stage (vs ~310 cycles
// of MFMA) regardless of traffic, occupancy, or load pattern — a full-CU
// convoy. Tiles are small (reuse factor 2 per operand), so fragments are
// loaded DIRECTLY global->VGPR: 2x L2 traffic (~3.2 GB @ ~35 TB/s ~ 90 us
// chip-wide) in exchange for zero synchronization. The 24-stage loop is
// fully unrolled: 192 independent coalesced 16B/lane loads + 384 MFMAs per
// wave, software-pipelined freely by the compiler (counted vmcnt, no
// barriers to drain). Accumulation order identical to R2: bit-exact.
__launch_bounds__(NTHREADS, 2)
__global__ void vq_main_kernel(const unsigned short* __restrict__ xpk,
                               const unsigned short* __restrict__ cbpk,
                               const float* __restrict__ csq,
                               float4* __restrict__ pairs) {
    __shared__ float4 pairs_sh[TM][2];   // 4 KB, epilogue only

    const int tid  = threadIdx.x;
    const int w    = tid >> 6;       // wave 0..3
    const int wy   = w >> 1;         // wave row (token dim)
    const int wx   = w & 1;          // wave col (code dim)
    const int lane = tid & 63;
    const int lm   = lane & 15;
    const int q    = lane >> 4;

    // XCD-grouped swizzle (bijective, nwg=4096 % 8 == 0): all 8 code-chunks
    // of one token group land on one XCD -> x slabs are L2-shared.
    const int bx     = blockIdx.x;
    const int jj     = bx >> 3;
    const int grp    = (bx & 7) + ((jj >> 3) << 3);
    const int cchunk = jj & 7;
    const int tok0   = grp * TM;
    const int code0  = cchunk * TN;

    float cs_reg[4];
#pragma unroll
    for (int ni = 0; ni < 4; ++ni)
        cs_reg[ni] = csq[code0 + wx * 64 + ni * 16 + lm];

    f32x4 acc[4][4];
#pragma unroll
    for (int mi = 0; mi < 4; ++mi)
#pragma unroll
        for (int ni = 0; ni < 4; ++ni)
            acc[mi][ni] = (f32x4){0.f, 0.f, 0.f, 0.f};

    // Per-lane fragment bases. A fragment (mi, stage): row wy*64+mi*16+lm,
    // k-octet q of chunk (grp*16 + pa + kc). Chunk = 4096 shorts (8 KB).
    // Lane addresses within a fragment load span a contiguous 1 KB: 16 rows
    // x 64 B, each lane a distinct 16 B -> perfectly coalesced.
    const unsigned short* abase =
        xpk + ((size_t)grp << 16) + (wy * 64 + lm) * 32 + q * 8;
    const unsigned short* bbase =
        cbpk + ((size_t)cchunk << 16) + (wx * 64 + lm) * 32 + q * 8;

#pragma unroll
    for (int s = 0; s < NSTAGE; ++s) {
        const int seg = s >> 3;
        const int kc  = s & 7;
        const int pa  = (seg == 2) ? 8 : 0;   // A: hi,hi,lo
        const int pb  = (seg == 1) ? 8 : 0;   // B: hi,lo,hi
        const unsigned short* ga = abase + (pa + kc) * 4096;
        const unsigned short* gb = bbase + (pb + kc) * 4096;

        bf16x8 af[4], bf[4];
#pragma unroll
        for (int mi = 0; mi < 4; ++mi)
            af[mi] = *reinterpret_cast<const bf16x8*>(ga + mi * 512);
#pragma unroll
        for (int ni = 0; ni < 4; ++ni)
            bf[ni] = *reinterpret_cast<const bf16x8*>(gb + ni * 512);

#pragma unroll
        for (int mi = 0; mi < 4; ++mi)
#pragma unroll
            for (int ni = 0; ni < 4; ++ni)
                acc[mi][ni] = __builtin_amdgcn_mfma_f32_16x16x32_bf16(
                    af[mi], bf[ni], acc[mi][ni], 0, 0, 0);
    }

    // Extraction: C/D layout row=(q*4+reg), col=lm per 16x16 tile (verified R6).
#pragma unroll
    for (int mi = 0; mi < 4; ++mi) {
#pragma unroll
        for (int r = 0; r < 4; ++r) {
            int row_local = wy * 64 + mi * 16 + q * 4 + r;
            float l1 = 3.4e38f, l2 = 3.4e38f;
            int   j1 = 0x7fffffff, j2 = 0x7fffffff;
#pragma unroll
            for (int ni = 0; ni < 4; ++ni) {
                float d = cs_reg[ni] - 2.0f * acc[mi][ni][r];
                ins2(d, code0 + wx * 64 + ni * 16 + lm, l1, j1, l2, j2);
            }
#pragma unroll
            for (int m = 1; m < 16; m <<= 1) {
                float o1 = __shfl_xor(l1, m);
                int   p1 = __shfl_xor(j1, m);
                float o2 = __shfl_xor(l2, m);
                int   p2 = __shfl_xor(j2, m);
                ins2(o1, p1, l1, j1, l2, j2);
                ins2(o2, p2, l1, j1, l2, j2);
            }
            if (lm == 0) {
                float4 pr;
                pr.x = l1; pr.y = l2;
                pr.z = __int_as_float(j1); pr.w = __int_as_float(j2);
                pairs_sh[row_local][wx] = pr;
            }
        }
    }
    __syncthreads();
    if (tid < TM) {
        float4 pa = pairs_sh[tid][0];
        float4 pb = pairs_sh[tid][1];
        float d1 = pa.x, d2 = pa.y;
        int   i1 = __float_as_int(pa.z), i2 = __float_as_int(pa.w);
        ins2(pb.x, __float_as_int(pb.z), d1, i1, d2, i2);
        ins2(pb.y, __float_as_int(pb.w), d1, i1, d2, i2);
        float4 pr;
        pr.x = d1; pr.y = d2;
        pr.z = __int_as_float(i1); pr.w = __int_as_float(i2);
        // chunk-major: contiguous 16B stores across tid (no write-amp)
        pairs[(size_t)cchunk * N_TOK + tok0 + tid] = pr;
    }
}

// Merge 8 chunk top-2 pairs (lexicographic, order-independent), then fp64
// refine near-ties with the collapse-tolerant tie-break (proven R4-R6).
__global__ void merge_refine_kernel(const float* __restrict__ x,
                                    const float* __restrict__ cb,
                                    const float4* __restrict__ pairs,
                                    int* __restrict__ idx_out) {
    int t = blockIdx.x * 256 + threadIdx.x;
    if (t >= N_TOK) return;
    float4 p0 = pairs[t];
    float d1 = p0.x, d2 = p0.y;
    int   i1 = __float_as_int(p0.z), i2 = __float_as_int(p0.w);
#pragma unroll
    for (int c = 1; c < NCHUNK; ++c) {
        float4 p = pairs[(size_t)c * N_TOK + t];
        ins2(p.x, __float_as_int(p.z), d1, i1, d2, i2);
        ins2(p.y, __float_as_int(p.w), d1, i1, d2, i2);
    }

    int pick = i1;
    if (d2 - d1 < REFINE_EPS) {
        const float* xr = x + (size_t)t * DIM;
        const float* c1 = cb + (size_t)i1 * DIM;
        const float* c2 = cb + (size_t)i2 * DIM;
        double sA = 0.0, dA = 0.0, sB = 0.0, dB = 0.0;
        for (int k = 0; k < DIM; ++k) {
            double xv = (double)xr[k];
            double a  = (double)c1[k];
            double b  = (double)c2[k];
            sA += a * a; dA += xv * a;
            sB += b * b; dB += xv * b;
        }
        double DA  = sA - 2.0 * dA;
        double DB  = sB - 2.0 * dB;
        double gap = DB - DA;
        if (gap > TIE_THETA)       pick = i1;
        else if (gap < -TIE_THETA) pick = i2;
        else                       pick = (i1 < i2) ? i1 : i2;
    }
    idx_out[t] = pick;
}

// Output: quantized rows (exact ref math: x + (q - x)), indices as float,
// commitment-loss partial sums. Overwrites the x-packed scratch in out_q.
__launch_bounds__(NTHREADS)
__global__ void output_kernel(const float* __restrict__ x,
                              const float* __restrict__ cb,
                              const int* __restrict__ idx,
                              float* __restrict__ out_q,
                              float* __restrict__ out_idx,
                              float* __restrict__ loss_ws) {
    __shared__ int   sh_idx[TM];
    __shared__ float wsum[4];
    const int tid  = threadIdx.x;
    const int tok0 = blockIdx.x * TM;

    if (tid < TM) sh_idx[tid] = idx[tok0 + tid];
    __syncthreads();

    float lsum = 0.0f;
    for (int t = 0; t < TM; ++t) {
        int code = sh_idx[t];
        float qv = cb[(size_t)code * DIM + tid];
        float xv = x[(size_t)(tok0 + t) * DIM + tid];
        out_q[(size_t)(tok0 + t) * DIM + tid] = xv + (qv - xv);
        float df = xv - qv;
        lsum = fmaf(df, df, lsum);
    }
    if (tid < TM) out_idx[tok0 + tid] = (float)sh_idx[tid];

#pragma unroll
    for (int off = 1; off < 64; off <<= 1) lsum += __shfl_xor(lsum, off);
    if ((tid & 63) == 0) wsum[tid >> 6] = lsum;
    __syncthreads();
    if (tid == 0) atomicAdd(loss_ws, (wsum[0] + wsum[1]) + (wsum[2] + wsum[3]));
}

__global__ void finalize_kernel(const float* ws, float* out_loss) {
    if (threadIdx.x == 0) out_loss[0] = ws[0] * (1.0f / 16777216.0f); // COMMITMENT * mean
}

extern "C" void kernel_launch(void* const* d_in, const int* in_sizes, int n_in,
                              void* d_out, int out_size, void* d_ws, size_t ws_size,
                              hipStream_t stream) {
    const float* x  = (const float*)d_in[0];   // [16,4096,256] fp32
    const float* cb = (const float*)d_in[1];   // [1024,256] fp32

    float* out      = (float*)d_out;
    float* out_q    = out;
    float* out_idx  = out + (size_t)N_TOK * DIM;
    float* out_loss = out_idx + N_TOK;

    float*  ws    = (float*)d_ws;
    float*  csq   = ws + WS_CSQ_OFF;
    int*    idx   = (int*)(ws + WS_IDX_OFF);
    float4* pairs = (float4*)(ws + WS_PAIRS_OFF);
    unsigned short* cbpk = (unsigned short*)(ws + WS_CBPK_OFF);
    // x packed bf16 hi/lo lives in the out_q region (64 MB, overwritten later)
    unsigned short* xpk  = (unsigned short*)out_q;

    zero_loss_kernel<<<1, 64, 0, stream>>>(ws);
    rowsq_np_kernel<<<KCODE / 16, 256, 0, stream>>>(cb, csq, KCODE);
    // x: 65536 rows * 32 threads/row = 2,097,152 threads; cb: 1024 * 32 = 32768
    pack_tiles_kernel<<<(N_TOK * 32) / 256, 256, 0, stream>>>(x, xpk, N_TOK * 32);
    pack_tiles_kernel<<<(KCODE * 32) / 256, 256, 0, stream>>>(cb, cbpk, KCODE * 32);
    vq_main_kernel<<<(N_TOK / TM) * NCHUNK, NTHREADS, 0, stream>>>(xpk, cbpk, csq, pairs);
    merge_refine_kernel<<<N_TOK / 256, 256, 0, stream>>>(x, cb, pairs, idx);
    output_kernel<<<N_TOK / TM, NTHREADS, 0, stream>>>(x, cb, idx, out_q, out_idx, ws);
    finalize_kernel<<<1, 64, 0, stream>>>(ws, out_loss);
}

// Round 4
// 897.391 us; speedup vs baseline: 1.3665x; 1.3665x over previous
//
#include <hip/hip_runtime.h>

// Problem constants: B=16, T=4096, D=256, K=1024
#define N_TOK 65536
#define DIM   256
#define KCODE 1024

#define NTHREADS 256
#define TM 128          // tokens per block
#define TN 128          // codes per block
#define NCHUNK 8        // code chunks (1024/128)
#define NSTAGE 24       // 3 segments x 8 k-chunks of 32

// fp32 gap below which the top-2 go to fp64 refinement (bf16x3 dot err ~1e-2 bound)
#define REFINE_EPS 0.125f
// fp64 gap below which the reference's fp32 pipeline likely collapsed the two
// distances onto the same fp32 grid point -> first-occurrence -> LOWER index.
#define TIE_THETA 1.0e-4

// ws layout (floats):
//   [0]                    loss accum
//   [16 .. 16+1024)        c_sq (numpy-pairwise-exact)
//   [2048 .. +65536)       idx (int) final argmin
//   [67584 .. +8*4*65536)  pairs (float4, chunk-major: pairs[c*N_TOK + t])
//   [then]                 cb packed tile-major bf16 hi/lo (1 MB)
#define WS_CSQ_OFF   16
#define WS_IDX_OFF   2048
#define WS_PAIRS_OFF (WS_IDX_OFF + N_TOK)
#define WS_CBPK_OFF  (WS_PAIRS_OFF + N_TOK * NCHUNK * 4)

typedef float f32x4  __attribute__((ext_vector_type(4)));
typedef short bf16x8 __attribute__((ext_vector_type(8)));
typedef short s16x8  __attribute__((ext_vector_type(8)));

__global__ void zero_loss_kernel(float* ws) {
    if (threadIdx.x == 0) ws[0] = 0.0f;
}

// numpy-pairwise-exact row sum-of-squares for [rows, 256] fp32 (codebook).
__global__ void rowsq_np_kernel(const float* __restrict__ m,
                                float* __restrict__ out, int rows) {
#pragma clang fp contract(off)
    int row = blockIdx.x * 16 + (threadIdx.x >> 4);
    int l   = threadIdx.x & 15;
    if (row >= rows) return;
    int h = l >> 3;
    int j = l & 7;
    const float* p = m + (size_t)row * DIM + h * 128 + j;
    float v = p[0];
    float r = v * v;
#pragma unroll
    for (int i = 1; i < 16; ++i) {
        float w  = p[i * 8];
        float w2 = w * w;
        r = r + w2;
    }
    float t = r + __shfl_xor(r, 1);
    t = t + __shfl_xor(t, 2);
    t = t + __shfl_xor(t, 4);
    t = t + __shfl_xor(t, 8);
    if (l == 0) out[row] = t;
}

// Insert (d, idx) into a sorted top-2 with lower-index tie-break.
__device__ __forceinline__ void ins2(float d, int idx,
                                     float& d1, int& i1, float& d2, int& i2) {
    if (d < d1 || (d == d1 && idx < i1)) {
        d2 = d1; i2 = i1; d1 = d; i1 = idx;
    } else if ((d < d2 || (d == d2 && idx < i2)) && idx != i1) {
        d2 = d; i2 = idx;
    }
}

// RNE fp32 -> bf16 split: v = hi + lo with lo capturing the residual.
__device__ __forceinline__ void f2bf_split(float v, short& hi, short& lo) {
    unsigned u = __float_as_uint(v);
    unsigned r = (u + 0x7fffu + ((u >> 16) & 1u)) >> 16;
    hi = (short)r;
    float hf = __uint_as_float(r << 16);
    float lf = v - hf;
    unsigned u2 = __float_as_uint(lf);
    unsigned r2 = (u2 + 0x7fffu + ((u2 >> 16) & 1u)) >> 16;
    lo = (short)r2;
}

// Tile-major pack, no swizzle (fragments are consumed straight from global).
// Output: chunk c = (g*16 + part*8 + kc), each chunk 128 rows x 32 shorts
// (8 KB contiguous). Row r slot s (8 shorts) = k-octet s of k-range
// [kc*32, kc*32+32). part: 0 = bf16 hi, 8 = bf16 lo.
// Thread (g, kc, r, s): reads 8 fp32, writes 16B hi + 16B lo, all coalesced.
__global__ void pack_tiles_kernel(const float* __restrict__ src,
                                  unsigned short* __restrict__ dst,
                                  int total) {       // total = rows * 32
    int tid = blockIdx.x * blockDim.x + threadIdx.x;
    if (tid >= total) return;
    int s   = tid & 3;
    int r   = (tid >> 2) & 127;
    int kc  = (tid >> 9) & 7;
    int g   = tid >> 12;

    const float4* xr = reinterpret_cast<const float4*>(
        src + ((size_t)(g * 128 + r)) * DIM + kc * 32 + s * 8);
    float4 v0 = xr[0];
    float4 v1 = xr[1];

    float f[8] = {v0.x, v0.y, v0.z, v0.w, v1.x, v1.y, v1.z, v1.w};
    s16x8 hv, lv;
#pragma unroll
    for (int i = 0; i < 8; ++i) {
        short h, l;
        f2bf_split(f[i], h, l);
        hv[i] = h; lv[i] = l;
    }
    size_t base_hi = (((size_t)(g * 16 + kc) * 128 + r) << 5) + s * 8;
    size_t base_lo = (((size_t)(g * 16 + 8 + kc) * 128 + r) << 5) + s * 8;
    *reinterpret_cast<s16x8*>(dst + base_hi) = hv;
    *reinterpret_cast<s16x8*>(dst + base_lo) = lv;
}

// MFMA distance + top-2. dist' = c_sq - 2*(x.c); ||x||^2 dropped (cancels).
// dot = hi*hi + hi*lo + lo*hi as one K=768 concat-GEMM over 3 segments.
//
// R4: no LDS, no K-loop barriers (validated direction from R3), but with a
// BOUNDED depth-2 register pipeline instead of R3's full unroll (which
// spilled: 705 MB scratch writes). Two NAMED fragment sets (static indexing
// only, rule #20), '#pragma unroll 1' so the scheduler cannot re-widen the
// live set. Issue order loads(s+1) / MFMA(s) yields counted vmcnt(8) —
// never drains to 0 (T4), possible only because there is no barrier.
// Registers: acc 64 + 2 frag sets 64 + addr/misc ~28 -> launch_bounds cap
// 170 (3 waves/EU, 12 waves/CU). Accumulation order identical to R2/R3.
__launch_bounds__(NTHREADS, 3)
__global__ void vq_main_kernel(const unsigned short* __restrict__ xpk,
                               const unsigned short* __restrict__ cbpk,
                               const float* __restrict__ csq,
                               float4* __restrict__ pairs) {
    __shared__ float4 pairs_sh[TM][2];   // 4 KB, epilogue only

    const int tid  = threadIdx.x;
    const int w    = tid >> 6;       // wave 0..3
    const int wy   = w >> 1;         // wave row (token dim)
    const int wx   = w & 1;          // wave col (code dim)
    const int lane = tid & 63;
    const int lm   = lane & 15;
    const int q    = lane >> 4;

    // XCD-grouped swizzle (bijective, nwg=4096 % 8 == 0): all 8 code-chunks
    // of one token group land on one XCD -> x slabs are L2-shared.
    const int bx     = blockIdx.x;
    const int jj     = bx >> 3;
    const int grp    = (bx & 7) + ((jj >> 3) << 3);
    const int cchunk = jj & 7;
    const int tok0   = grp * TM;
    const int code0  = cchunk * TN;

    float cs_reg[4];
#pragma unroll
    for (int ni = 0; ni < 4; ++ni)
        cs_reg[ni] = csq[code0 + wx * 64 + ni * 16 + lm];

    f32x4 acc[4][4];
#pragma unroll
    for (int mi = 0; mi < 4; ++mi)
#pragma unroll
        for (int ni = 0; ni < 4; ++ni)
            acc[mi][ni] = (f32x4){0.f, 0.f, 0.f, 0.f};

    // Per-lane fragment bases. A fragment (mi): rows wy*64+mi*16+[0,16),
    // k-octet q, within chunk (grp*16 + pa + kc); chunk = 4096 shorts (8 KB).
    // A wave's 64 lanes cover a dense 1 KB span per fragment load.
    const unsigned short* abase =
        xpk + ((size_t)grp << 16) + (wy * 64 + lm) * 32 + q * 8;
    const unsigned short* bbase =
        cbpk + ((size_t)cchunk << 16) + (wx * 64 + lm) * 32 + q * 8;

    bf16x8 af0[4], bf0[4], af1[4], bf1[4];

    // stage s: seg = s>>3; A part: hi,hi,lo ; B part: hi,lo,hi
    auto issue = [&](int s, bf16x8* af, bf16x8* bf) {
        const int kc = s & 7;
        const int pa = (s >= 16) ? 8 : 0;
        const int pb = (s >= 8 && s < 16) ? 8 : 0;
        const unsigned short* ga = abase + (pa + kc) * 4096;
        const unsigned short* gb = bbase + (pb + kc) * 4096;
#pragma unroll
        for (int mi = 0; mi < 4; ++mi)
            af[mi] = *reinterpret_cast<const bf16x8*>(ga + mi * 512);
#pragma unroll
        for (int ni = 0; ni < 4; ++ni)
            bf[ni] = *reinterpret_cast<const bf16x8*>(gb + ni * 512);
    };
    auto compute = [&](const bf16x8* af, const bf16x8* bf) {
#pragma unroll
        for (int mi = 0; mi < 4; ++mi)
#pragma unroll
            for (int ni = 0; ni < 4; ++ni)
                acc[mi][ni] = __builtin_amdgcn_mfma_f32_16x16x32_bf16(
                    af[mi], bf[ni], acc[mi][ni], 0, 0, 0);
    };

    issue(0, af0, bf0);
#pragma unroll 1
    for (int s = 0; s < NSTAGE; s += 2) {
        issue(s + 1, af1, bf1);     // 8 loads in flight over compute(s)
        compute(af0, bf0);          // compiler waits vmcnt(8), not 0
        if (s + 2 < NSTAGE) issue(s + 2, af0, bf0);
        compute(af1, bf1);
    }

    // Extraction: C/D layout row=(q*4+reg), col=lm per 16x16 tile (verified R6).
#pragma unroll
    for (int mi = 0; mi < 4; ++mi) {
#pragma unroll
        for (int r = 0; r < 4; ++r) {
            int row_local = wy * 64 + mi * 16 + q * 4 + r;
            float l1 = 3.4e38f, l2 = 3.4e38f;
            int   j1 = 0x7fffffff, j2 = 0x7fffffff;
#pragma unroll
            for (int ni = 0; ni < 4; ++ni) {
                float d = cs_reg[ni] - 2.0f * acc[mi][ni][r];
                ins2(d, code0 + wx * 64 + ni * 16 + lm, l1, j1, l2, j2);
            }
#pragma unroll
            for (int m = 1; m < 16; m <<= 1) {
                float o1 = __shfl_xor(l1, m);
                int   p1 = __shfl_xor(j1, m);
                float o2 = __shfl_xor(l2, m);
                int   p2 = __shfl_xor(j2, m);
                ins2(o1, p1, l1, j1, l2, j2);
                ins2(o2, p2, l1, j1, l2, j2);
            }
            if (lm == 0) {
                float4 pr;
                pr.x = l1; pr.y = l2;
                pr.z = __int_as_float(j1); pr.w = __int_as_float(j2);
                pairs_sh[row_local][wx] = pr;
            }
        }
    }
    __syncthreads();
    if (tid < TM) {
        float4 pa = pairs_sh[tid][0];
        float4 pb = pairs_sh[tid][1];
        float d1 = pa.x, d2 = pa.y;
        int   i1 = __float_as_int(pa.z), i2 = __float_as_int(pa.w);
        ins2(pb.x, __float_as_int(pb.z), d1, i1, d2, i2);
        ins2(pb.y, __float_as_int(pb.w), d1, i1, d2, i2);
        float4 pr;
        pr.x = d1; pr.y = d2;
        pr.z = __int_as_float(i1); pr.w = __int_as_float(i2);
        // chunk-major: contiguous 16B stores across tid (no write-amp)
        pairs[(size_t)cchunk * N_TOK + tok0 + tid] = pr;
    }
}

// Merge 8 chunk top-2 pairs (lexicographic, order-independent), then fp64
// refine near-ties with the collapse-tolerant tie-break (proven R4-R6).
__global__ void merge_refine_kernel(const float* __restrict__ x,
                                    const float* __restrict__ cb,
                                    const float4* __restrict__ pairs,
                                    int* __restrict__ idx_out) {
    int t = blockIdx.x * 256 + threadIdx.x;
    if (t >= N_TOK) return;
    float4 p0 = pairs[t];
    float d1 = p0.x, d2 = p0.y;
    int   i1 = __float_as_int(p0.z), i2 = __float_as_int(p0.w);
#pragma unroll
    for (int c = 1; c < NCHUNK; ++c) {
        float4 p = pairs[(size_t)c * N_TOK + t];
        ins2(p.x, __float_as_int(p.z), d1, i1, d2, i2);
        ins2(p.y, __float_as_int(p.w), d1, i1, d2, i2);
    }

    int pick = i1;
    if (d2 - d1 < REFINE_EPS) {
        const float* xr = x + (size_t)t * DIM;
        const float* c1 = cb + (size_t)i1 * DIM;
        const float* c2 = cb + (size_t)i2 * DIM;
        double sA = 0.0, dA = 0.0, sB = 0.0, dB = 0.0;
        for (int k = 0; k < DIM; ++k) {
            double xv = (double)xr[k];
            double a  = (double)c1[k];
            double b  = (double)c2[k];
            sA += a * a; dA += xv * a;
            sB += b * b; dB += xv * b;
        }
        double DA  = sA - 2.0 * dA;
        double DB  = sB - 2.0 * dB;
        double gap = DB - DA;
        if (gap > TIE_THETA)       pick = i1;
        else if (gap < -TIE_THETA) pick = i2;
        else                       pick = (i1 < i2) ? i1 : i2;
    }
    idx_out[t] = pick;
}

// Output: quantized rows (exact ref math: x + (q - x)), indices as float,
// commitment-loss partial sums. Overwrites the x-packed scratch in out_q.
__launch_bounds__(NTHREADS)
__global__ void output_kernel(const float* __restrict__ x,
                              const float* __restrict__ cb,
                              const int* __restrict__ idx,
                              float* __restrict__ out_q,
                              float* __restrict__ out_idx,
                              float* __restrict__ loss_ws) {
    __shared__ int   sh_idx[TM];
    __shared__ float wsum[4];
    const int tid  = threadIdx.x;
    const int tok0 = blockIdx.x * TM;

    if (tid < TM) sh_idx[tid] = idx[tok0 + tid];
    __syncthreads();

    float lsum = 0.0f;
    for (int t = 0; t < TM; ++t) {
        int code = sh_idx[t];
        float qv = cb[(size_t)code * DIM + tid];
        float xv = x[(size_t)(tok0 + t) * DIM + tid];
        out_q[(size_t)(tok0 + t) * DIM + tid] = xv + (qv - xv);
        float df = xv - qv;
        lsum = fmaf(df, df, lsum);
    }
    if (tid < TM) out_idx[tok0 + tid] = (float)sh_idx[tid];

#pragma unroll
    for (int off = 1; off < 64; off <<= 1) lsum += __shfl_xor(lsum, off);
    if ((tid & 63) == 0) wsum[tid >> 6] = lsum;
    __syncthreads();
    if (tid == 0) atomicAdd(loss_ws, (wsum[0] + wsum[1]) + (wsum[2] + wsum[3]));
}

__global__ void finalize_kernel(const float* ws, float* out_loss) {
    if (threadIdx.x == 0) out_loss[0] = ws[0] * (1.0f / 16777216.0f); // COMMITMENT * mean
}

extern "C" void kernel_launch(void* const* d_in, const int* in_sizes, int n_in,
                              void* d_out, int out_size, void* d_ws, size_t ws_size,
                              hipStream_t stream) {
    const float* x  = (const float*)d_in[0];   // [16,4096,256] fp32
    const float* cb = (const float*)d_in[1];   // [1024,256] fp32

    float* out      = (float*)d_out;
    float* out_q    = out;
    float* out_idx  = out + (size_t)N_TOK * DIM;
    float* out_loss = out_idx + N_TOK;

    float*  ws    = (float*)d_ws;
    float*  csq   = ws + WS_CSQ_OFF;
    int*    idx   = (int*)(ws + WS_IDX_OFF);
    float4* pairs = (float4*)(ws + WS_PAIRS_OFF);
    unsigned short* cbpk = (unsigned short*)(ws + WS_CBPK_OFF);
    // x packed bf16 hi/lo lives in the out_q region (64 MB, overwritten later)
    unsigned short* xpk  = (unsigned short*)out_q;

    zero_loss_kernel<<<1, 64, 0, stream>>>(ws);
    rowsq_np_kernel<<<KCODE / 16, 256, 0, stream>>>(cb, csq, KCODE);
    // x: 65536 rows * 32 threads/row = 2,097,152 threads; cb: 1024 * 32 = 32768
    pack_tiles_kernel<<<(N_TOK * 32) / 256, 256, 0, stream>>>(x, xpk, N_TOK * 32);
    pack_tiles_kernel<<<(KCODE * 32) / 256, 256, 0, stream>>>(cb, cbpk, KCODE * 32);
    vq_main_kernel<<<(N_TOK / TM) * NCHUNK, NTHREADS, 0, stream>>>(xpk, cbpk, csq, pairs);
    merge_refine_kernel<<<N_TOK / 256, 256, 0, stream>>>(x, cb, pairs, idx);
    output_kernel<<<N_TOK / TM, NTHREADS, 0, stream>>>(x, cb, idx, out_q, out_idx, ws);
    finalize_kernel<<<1, 64, 0, stream>>>(ws, out_loss);
}